// Round 12
// baseline (121.212 us; speedup 1.0000x reference)
//
#include <hip/hip_runtime.h>
#include <hip/hip_bf16.h>
#include <hip/hip_fp16.h>

#define KDIM 8
#define MAT 64  // KDIM*KDIM
#define NTERMS 4

// ---------------------------------------------------------------------------
// Phase 1: 8 lanes per edge; lane r computes ROW r of U[e] = expm(skew(w)),
// stored as fp16 (one 16B packed row per lane; 128B contiguous per edge).
// ~39us vs ~30us memory floor (128MB read + 64MB write at 6.3TB/s) — leave.
// ---------------------------------------------------------------------------
__global__ __launch_bounds__(256, 4)
void expm_edges_kernel(const float* __restrict__ omega_params,
                       __half* __restrict__ U, int E) {
    int t = blockIdx.x * blockDim.x + threadIdx.x;
    int e = t >> 3;   // edge
    int r = t & 7;    // output row of U (= column of exp(A'))
    if (e >= E) return;

    // Load full omega (row-major 8x8) via float4, unpack into scalars.
    float w[MAT];
    const float4* src = (const float4*)(omega_params + (size_t)e * MAT);
    #pragma unroll
    for (int i = 0; i < MAT / 4; ++i) {
        float4 v = src[i];
        w[4 * i + 0] = v.x;
        w[4 * i + 1] = v.y;
        w[4 * i + 2] = v.z;
        w[4 * i + 3] = v.w;
    }

    // In-place: w <- A' = 0.5*(w^T - w).
    #pragma unroll
    for (int i = 0; i < KDIM; ++i) {
        w[i * KDIM + i] = 0.0f;
        #pragma unroll
        for (int j = i + 1; j < KDIM; ++j) {
            float s = 0.5f * (w[j * KDIM + i] - w[i * KDIM + j]);
            w[i * KDIM + j] = s;
            w[j * KDIM + i] = -s;
        }
    }

    // t = column r of I.
    float tc[KDIM];
    #pragma unroll
    for (int i = 0; i < KDIM; ++i) tc[i] = (i == r) ? 1.0f : 0.0f;

    // Horner: t <- e_r + (A'*t)/k for k = NTERMS..1.
    #pragma unroll
    for (int k = NTERMS; k >= 1; --k) {
        const float inv = 1.0f / (float)k;
        float tmp[KDIM];
        #pragma unroll
        for (int i = 0; i < KDIM; ++i) {
            float acc = 0.0f;
            #pragma unroll
            for (int m = 0; m < KDIM; ++m)
                acc += w[i * KDIM + m] * tc[m];
            tmp[i] = acc;
        }
        #pragma unroll
        for (int i = 0; i < KDIM; ++i)
            tc[i] = tmp[i] * inv + ((i == r) ? 1.0f : 0.0f);
    }

    // Pack row r to fp16 and store 16B; the 8-lane group writes 128B contig.
    __half2 h0 = __floats2half2_rn(tc[0], tc[1]);
    __half2 h1 = __floats2half2_rn(tc[2], tc[3]);
    __half2 h2 = __floats2half2_rn(tc[4], tc[5]);
    __half2 h3 = __floats2half2_rn(tc[6], tc[7]);
    uint4 pack;
    pack.x = __builtin_bit_cast(unsigned int, h0);
    pack.y = __builtin_bit_cast(unsigned int, h1);
    pack.z = __builtin_bit_cast(unsigned int, h2);
    pack.w = __builtin_bit_cast(unsigned int, h3);
    *(uint4*)(U + (size_t)e * MAT + r * KDIM) = pack;
}

// ---------------------------------------------------------------------------
// Phase 2: grid-stride, 8 lanes per event, 8 events per group per iteration.
// R11: 4-way MLP got 73us (HBM 38%, VALU 10%) -> still latency-bound on the
// idx->U chains (~21 random lines in flight per SIMD). This version batches
// 8 independent chains per iteration (phase-split: 8 idx loads, then 8
// U-line loads, then 8 compute+store) at ~80 VGPR, doubling per-SIMD MLP
// while staying under the (256,4) 128-VGPR cap. Coalescing preserved.
// ---------------------------------------------------------------------------
__global__ __launch_bounds__(256, 4)
void transport_kernel(const __half* __restrict__ U,
                      const float* __restrict__ J,
                      const int* __restrict__ edge_indices,
                      float* __restrict__ out, int B) {
    const int tid = blockIdx.x * blockDim.x + threadIdx.x;
    const int r = tid & 7;
    const int g0 = tid >> 3;                            // group id
    const int G = (gridDim.x * blockDim.x) >> 3;        // total groups

    int ev = g0;

    // Main loop: 8 independent events per iteration.
    for (; ev + 7 * G < B; ev += 8 * G) {
        // Phase A: 8 independent idx loads.
        int e[8];
        #pragma unroll
        for (int q = 0; q < 8; ++q) e[q] = edge_indices[ev + q * G];

        // Phase B: 8 independent random U-line loads (one 16B row each).
        uint4 up[8];
        #pragma unroll
        for (int q = 0; q < 8; ++q)
            up[q] = *(const uint4*)(U + (size_t)e[q] * MAT + r * KDIM);

        // Phase C: per-event J load, dot, store (J/out are streaming).
        #pragma unroll
        for (int q = 0; q < 8; ++q) {
            const int evq = ev + q * G;
            const float4* Jr = (const float4*)(J + (size_t)evq * KDIM);
            const float4 a = Jr[0], b = Jr[1];
            float2 u0 = __half22float2(__builtin_bit_cast(__half2, up[q].x));
            float2 u1 = __half22float2(__builtin_bit_cast(__half2, up[q].y));
            float2 u2 = __half22float2(__builtin_bit_cast(__half2, up[q].z));
            float2 u3 = __half22float2(__builtin_bit_cast(__half2, up[q].w));
            out[(size_t)evq * KDIM + r] =
                u0.x * a.x + u0.y * a.y + u1.x * a.z + u1.y * a.w +
                u2.x * b.x + u2.y * b.y + u3.x * b.z + u3.y * b.w;
        }
    }

    // Remainder.
    for (; ev < B; ev += G) {
        const int e = edge_indices[ev];
        const uint4 up = *(const uint4*)(U + (size_t)e * MAT + r * KDIM);
        const float4* Jr = (const float4*)(J + (size_t)ev * KDIM);
        const float4 a = Jr[0], b = Jr[1];
        float2 u0 = __half22float2(__builtin_bit_cast(__half2, up.x));
        float2 u1 = __half22float2(__builtin_bit_cast(__half2, up.y));
        float2 u2 = __half22float2(__builtin_bit_cast(__half2, up.z));
        float2 u3 = __half22float2(__builtin_bit_cast(__half2, up.w));
        out[(size_t)ev * KDIM + r] =
            u0.x * a.x + u0.y * a.y + u1.x * a.z + u1.y * a.w +
            u2.x * b.x + u2.y * b.y + u3.x * b.z + u3.y * b.w;
    }
}

extern "C" void kernel_launch(void* const* d_in, const int* in_sizes, int n_in,
                              void* d_out, int out_size, void* d_ws, size_t ws_size,
                              hipStream_t stream) {
    const float* omega_params = (const float*)d_in[0];   // (E, 8, 8) f32
    const float* J            = (const float*)d_in[1];   // (B, 8)    f32
    const int*   edge_indices = (const int*)d_in[2];     // (B,)      int
    // d_in[3] = edges (E,2) — unused by the reference computation.

    const int E = in_sizes[0] / MAT;
    const int B = in_sizes[2];
    float* out = (float*)d_out;

    __half* U = (__half*)d_ws;  // E*64 halves = 64 MB; ws_size is ample.

    // Phase 1: per-edge matrix exponential, 8 lanes per edge, fp16 output.
    {
        int block = 256;
        long long total = (long long)E * KDIM;
        int grid = (int)((total + block - 1) / block);
        expm_edges_kernel<<<grid, block, 0, stream>>>(omega_params, U, E);
    }
    // Phase 2: gathered mat-vec, grid-stride at 2048 blocks, 8-way batched.
    {
        int block = 256;
        int grid = 2048;
        transport_kernel<<<grid, block, 0, stream>>>(U, J, edge_indices, out, B);
    }
}

// Round 13
// 114.905 us; speedup vs baseline: 1.0549x; 1.0549x over previous
//
#include <hip/hip_runtime.h>
#include <hip/hip_bf16.h>
#include <hip/hip_fp16.h>

#define KDIM 8
#define MAT 64  // KDIM*KDIM
#define NTERMS 4

// ---------------------------------------------------------------------------
// Phase 1: 8 lanes per edge; lane r computes ROW r of U[e] = expm(skew(w)),
// stored as fp16 (one 16B packed row per lane; 128B contiguous per edge).
// ~39us vs ~30us memory floor — unchanged this round (single-variable exp).
// ---------------------------------------------------------------------------
__global__ __launch_bounds__(256, 4)
void expm_edges_kernel(const float* __restrict__ omega_params,
                       __half* __restrict__ U, int E) {
    int t = blockIdx.x * blockDim.x + threadIdx.x;
    int e = t >> 3;   // edge
    int r = t & 7;    // output row of U (= column of exp(A'))
    if (e >= E) return;

    // Load full omega (row-major 8x8) via float4, unpack into scalars.
    float w[MAT];
    const float4* src = (const float4*)(omega_params + (size_t)e * MAT);
    #pragma unroll
    for (int i = 0; i < MAT / 4; ++i) {
        float4 v = src[i];
        w[4 * i + 0] = v.x;
        w[4 * i + 1] = v.y;
        w[4 * i + 2] = v.z;
        w[4 * i + 3] = v.w;
    }

    // In-place: w <- A' = 0.5*(w^T - w).
    #pragma unroll
    for (int i = 0; i < KDIM; ++i) {
        w[i * KDIM + i] = 0.0f;
        #pragma unroll
        for (int j = i + 1; j < KDIM; ++j) {
            float s = 0.5f * (w[j * KDIM + i] - w[i * KDIM + j]);
            w[i * KDIM + j] = s;
            w[j * KDIM + i] = -s;
        }
    }

    // t = column r of I.
    float tc[KDIM];
    #pragma unroll
    for (int i = 0; i < KDIM; ++i) tc[i] = (i == r) ? 1.0f : 0.0f;

    // Horner: t <- e_r + (A'*t)/k for k = NTERMS..1.
    #pragma unroll
    for (int k = NTERMS; k >= 1; --k) {
        const float inv = 1.0f / (float)k;
        float tmp[KDIM];
        #pragma unroll
        for (int i = 0; i < KDIM; ++i) {
            float acc = 0.0f;
            #pragma unroll
            for (int m = 0; m < KDIM; ++m)
                acc += w[i * KDIM + m] * tc[m];
            tmp[i] = acc;
        }
        #pragma unroll
        for (int i = 0; i < KDIM; ++i)
            tc[i] = tmp[i] * inv + ((i == r) ? 1.0f : 0.0f);
    }

    // Pack row r to fp16 and store 16B; the 8-lane group writes 128B contig.
    __half2 h0 = __floats2half2_rn(tc[0], tc[1]);
    __half2 h1 = __floats2half2_rn(tc[2], tc[3]);
    __half2 h2 = __floats2half2_rn(tc[4], tc[5]);
    __half2 h3 = __floats2half2_rn(tc[6], tc[7]);
    uint4 pack;
    pack.x = __builtin_bit_cast(unsigned int, h0);
    pack.y = __builtin_bit_cast(unsigned int, h1);
    pack.z = __builtin_bit_cast(unsigned int, h2);
    pack.w = __builtin_bit_cast(unsigned int, h3);
    *(uint4*)(U + (size_t)e * MAT + r * KDIM) = pack;
}

// ---------------------------------------------------------------------------
// Phase 2: grid-stride, 8 lanes per event, 4 events/group/iter (R11 structure,
// 73us) + software-pipelined idx prefetch. R12 showed 8-way batching is
// defeated by the allocator (VGPR stayed 36, occupancy fell). Instead shorten
// the serial chain: idx(~200cy) -> U line(~500cy). Prologue loads batch 0's
// indices; each iteration issues the 4 random U loads FIRST (addresses known),
// prefetches the next batch's indices, then loads J / computes / stores.
// Steady-state chain = U latency only.
// ---------------------------------------------------------------------------
__global__ __launch_bounds__(256, 4)
void transport_kernel(const __half* __restrict__ U,
                      const float* __restrict__ J,
                      const int* __restrict__ edge_indices,
                      float* __restrict__ out, int B) {
    const int tid = blockIdx.x * blockDim.x + threadIdx.x;
    const int r = tid & 7;
    const int g0 = tid >> 3;                            // group id
    const int G = (gridDim.x * blockDim.x) >> 3;        // total groups

    int ev = g0;
    int e0 = 0, e1 = 0, e2 = 0, e3 = 0;

    // Prologue: load first batch's indices.
    if (ev + 3 * G < B) {
        e0 = edge_indices[ev];
        e1 = edge_indices[ev + G];
        e2 = edge_indices[ev + 2 * G];
        e3 = edge_indices[ev + 3 * G];
    }

    for (; ev + 3 * G < B; ) {
        const int ev0 = ev, ev1 = ev + G, ev2 = ev + 2 * G, ev3 = ev + 3 * G;

        // Issue the 4 independent random U-line loads immediately.
        const uint4 up0 = *(const uint4*)(U + (size_t)e0 * MAT + r * KDIM);
        const uint4 up1 = *(const uint4*)(U + (size_t)e1 * MAT + r * KDIM);
        const uint4 up2 = *(const uint4*)(U + (size_t)e2 * MAT + r * KDIM);
        const uint4 up3 = *(const uint4*)(U + (size_t)e3 * MAT + r * KDIM);

        // Prefetch next batch's indices (hides idx latency under this batch).
        const int evn = ev + 4 * G;
        if (evn + 3 * G < B) {
            e0 = edge_indices[evn];
            e1 = edge_indices[evn + G];
            e2 = edge_indices[evn + 2 * G];
            e3 = edge_indices[evn + 3 * G];
        }

        // J loads (streaming, L2-friendly).
        const float4* J0 = (const float4*)(J + (size_t)ev0 * KDIM);
        const float4* J1 = (const float4*)(J + (size_t)ev1 * KDIM);
        const float4* J2 = (const float4*)(J + (size_t)ev2 * KDIM);
        const float4* J3 = (const float4*)(J + (size_t)ev3 * KDIM);
        const float4 a0 = J0[0], b0 = J0[1];
        const float4 a1 = J1[0], b1 = J1[1];
        const float4 a2 = J2[0], b2 = J2[1];
        const float4 a3 = J3[0], b3 = J3[1];

        float2 u0, u1, u2, u3;

        u0 = __half22float2(__builtin_bit_cast(__half2, up0.x));
        u1 = __half22float2(__builtin_bit_cast(__half2, up0.y));
        u2 = __half22float2(__builtin_bit_cast(__half2, up0.z));
        u3 = __half22float2(__builtin_bit_cast(__half2, up0.w));
        out[(size_t)ev0 * KDIM + r] =
            u0.x * a0.x + u0.y * a0.y + u1.x * a0.z + u1.y * a0.w +
            u2.x * b0.x + u2.y * b0.y + u3.x * b0.z + u3.y * b0.w;

        u0 = __half22float2(__builtin_bit_cast(__half2, up1.x));
        u1 = __half22float2(__builtin_bit_cast(__half2, up1.y));
        u2 = __half22float2(__builtin_bit_cast(__half2, up1.z));
        u3 = __half22float2(__builtin_bit_cast(__half2, up1.w));
        out[(size_t)ev1 * KDIM + r] =
            u0.x * a1.x + u0.y * a1.y + u1.x * a1.z + u1.y * a1.w +
            u2.x * b1.x + u2.y * b1.y + u3.x * b1.z + u3.y * b1.w;

        u0 = __half22float2(__builtin_bit_cast(__half2, up2.x));
        u1 = __half22float2(__builtin_bit_cast(__half2, up2.y));
        u2 = __half22float2(__builtin_bit_cast(__half2, up2.z));
        u3 = __half22float2(__builtin_bit_cast(__half2, up2.w));
        out[(size_t)ev2 * KDIM + r] =
            u0.x * a2.x + u0.y * a2.y + u1.x * a2.z + u1.y * a2.w +
            u2.x * b2.x + u2.y * b2.y + u3.x * b2.z + u3.y * b2.w;

        u0 = __half22float2(__builtin_bit_cast(__half2, up3.x));
        u1 = __half22float2(__builtin_bit_cast(__half2, up3.y));
        u2 = __half22float2(__builtin_bit_cast(__half2, up3.z));
        u3 = __half22float2(__builtin_bit_cast(__half2, up3.w));
        out[(size_t)ev3 * KDIM + r] =
            u0.x * a3.x + u0.y * a3.y + u1.x * a3.z + u1.y * a3.w +
            u2.x * b3.x + u2.y * b3.y + u3.x * b3.z + u3.y * b3.w;

        ev = evn;
    }

    // Remainder.
    for (; ev < B; ev += G) {
        const int e = edge_indices[ev];
        const uint4 up = *(const uint4*)(U + (size_t)e * MAT + r * KDIM);
        const float4* Jr = (const float4*)(J + (size_t)ev * KDIM);
        const float4 a = Jr[0], b = Jr[1];
        float2 u0 = __half22float2(__builtin_bit_cast(__half2, up.x));
        float2 u1 = __half22float2(__builtin_bit_cast(__half2, up.y));
        float2 u2 = __half22float2(__builtin_bit_cast(__half2, up.z));
        float2 u3 = __half22float2(__builtin_bit_cast(__half2, up.w));
        out[(size_t)ev * KDIM + r] =
            u0.x * a.x + u0.y * a.y + u1.x * a.z + u1.y * a.w +
            u2.x * b.x + u2.y * b.y + u3.x * b.z + u3.y * b.w;
    }
}

extern "C" void kernel_launch(void* const* d_in, const int* in_sizes, int n_in,
                              void* d_out, int out_size, void* d_ws, size_t ws_size,
                              hipStream_t stream) {
    const float* omega_params = (const float*)d_in[0];   // (E, 8, 8) f32
    const float* J            = (const float*)d_in[1];   // (B, 8)    f32
    const int*   edge_indices = (const int*)d_in[2];     // (B,)      int
    // d_in[3] = edges (E,2) — unused by the reference computation.

    const int E = in_sizes[0] / MAT;
    const int B = in_sizes[2];
    float* out = (float*)d_out;

    __half* U = (__half*)d_ws;  // E*64 halves = 64 MB; ws_size is ample.

    // Phase 1: per-edge matrix exponential, 8 lanes per edge, fp16 output.
    {
        int block = 256;
        long long total = (long long)E * KDIM;
        int grid = (int)((total + block - 1) / block);
        expm_edges_kernel<<<grid, block, 0, stream>>>(omega_params, U, E);
    }
    // Phase 2: gathered mat-vec, grid-stride 2048 blocks, 4-way + idx pipeline.
    {
        int block = 256;
        int grid = 2048;
        transport_kernel<<<grid, block, 0, stream>>>(U, J, edge_indices, out, B);
    }
}

// Round 14
// 111.080 us; speedup vs baseline: 1.0912x; 1.0344x over previous
//
#include <hip/hip_runtime.h>
#include <hip/hip_bf16.h>
#include <hip/hip_fp16.h>

#define KDIM 8
#define MAT 64  // KDIM*KDIM
#define NTERMS 4

// ---------------------------------------------------------------------------
// Phase 1: 8 lanes per edge; lane r computes ROW r of U[e] = expm(skew(w)),
// stored as fp16 (one 16B packed row per lane; 128B contiguous per edge).
// ~39us vs ~30us memory floor — unchanged this round (single-variable exp).
// ---------------------------------------------------------------------------
__global__ __launch_bounds__(256, 4)
void expm_edges_kernel(const float* __restrict__ omega_params,
                       __half* __restrict__ U, int E) {
    int t = blockIdx.x * blockDim.x + threadIdx.x;
    int e = t >> 3;   // edge
    int r = t & 7;    // output row of U (= column of exp(A'))
    if (e >= E) return;

    // Load full omega (row-major 8x8) via float4, unpack into scalars.
    float w[MAT];
    const float4* src = (const float4*)(omega_params + (size_t)e * MAT);
    #pragma unroll
    for (int i = 0; i < MAT / 4; ++i) {
        float4 v = src[i];
        w[4 * i + 0] = v.x;
        w[4 * i + 1] = v.y;
        w[4 * i + 2] = v.z;
        w[4 * i + 3] = v.w;
    }

    // In-place: w <- A' = 0.5*(w^T - w).
    #pragma unroll
    for (int i = 0; i < KDIM; ++i) {
        w[i * KDIM + i] = 0.0f;
        #pragma unroll
        for (int j = i + 1; j < KDIM; ++j) {
            float s = 0.5f * (w[j * KDIM + i] - w[i * KDIM + j]);
            w[i * KDIM + j] = s;
            w[j * KDIM + i] = -s;
        }
    }

    // t = column r of I.
    float tc[KDIM];
    #pragma unroll
    for (int i = 0; i < KDIM; ++i) tc[i] = (i == r) ? 1.0f : 0.0f;

    // Horner: t <- e_r + (A'*t)/k for k = NTERMS..1.
    #pragma unroll
    for (int k = NTERMS; k >= 1; --k) {
        const float inv = 1.0f / (float)k;
        float tmp[KDIM];
        #pragma unroll
        for (int i = 0; i < KDIM; ++i) {
            float acc = 0.0f;
            #pragma unroll
            for (int m = 0; m < KDIM; ++m)
                acc += w[i * KDIM + m] * tc[m];
            tmp[i] = acc;
        }
        #pragma unroll
        for (int i = 0; i < KDIM; ++i)
            tc[i] = tmp[i] * inv + ((i == r) ? 1.0f : 0.0f);
    }

    // Pack row r to fp16 and store 16B; the 8-lane group writes 128B contig.
    __half2 h0 = __floats2half2_rn(tc[0], tc[1]);
    __half2 h1 = __floats2half2_rn(tc[2], tc[3]);
    __half2 h2 = __floats2half2_rn(tc[4], tc[5]);
    __half2 h3 = __floats2half2_rn(tc[6], tc[7]);
    uint4 pack;
    pack.x = __builtin_bit_cast(unsigned int, h0);
    pack.y = __builtin_bit_cast(unsigned int, h1);
    pack.z = __builtin_bit_cast(unsigned int, h2);
    pack.w = __builtin_bit_cast(unsigned int, h3);
    *(uint4*)(U + (size_t)e * MAT + r * KDIM) = pack;
}

// ---------------------------------------------------------------------------
// Phase 2: grid-stride, 8 lanes per event, 4 events/group/iter + idx prefetch
// (R13 body, unchanged). This round's single variable: occupancy.
// R11-R13 plateau at ~73us with occ 57-66% and grid == 1x device wave
// capacity; VGPR=36 permits 8 waves/SIMD but (256,4) + exact-fit grid never
// requests them. Now: __launch_bounds__(256,8) + 4096 blocks (2x capacity,
// ~4 iters/group) to double resident waves -> 2x outstanding random chains.
// ---------------------------------------------------------------------------
__global__ __launch_bounds__(256, 8)
void transport_kernel(const __half* __restrict__ U,
                      const float* __restrict__ J,
                      const int* __restrict__ edge_indices,
                      float* __restrict__ out, int B) {
    const int tid = blockIdx.x * blockDim.x + threadIdx.x;
    const int r = tid & 7;
    const int g0 = tid >> 3;                            // group id
    const int G = (gridDim.x * blockDim.x) >> 3;        // total groups

    int ev = g0;
    int e0 = 0, e1 = 0, e2 = 0, e3 = 0;

    // Prologue: load first batch's indices.
    if (ev + 3 * G < B) {
        e0 = edge_indices[ev];
        e1 = edge_indices[ev + G];
        e2 = edge_indices[ev + 2 * G];
        e3 = edge_indices[ev + 3 * G];
    }

    for (; ev + 3 * G < B; ) {
        const int ev0 = ev, ev1 = ev + G, ev2 = ev + 2 * G, ev3 = ev + 3 * G;

        // Issue the 4 independent random U-line loads immediately.
        const uint4 up0 = *(const uint4*)(U + (size_t)e0 * MAT + r * KDIM);
        const uint4 up1 = *(const uint4*)(U + (size_t)e1 * MAT + r * KDIM);
        const uint4 up2 = *(const uint4*)(U + (size_t)e2 * MAT + r * KDIM);
        const uint4 up3 = *(const uint4*)(U + (size_t)e3 * MAT + r * KDIM);

        // Prefetch next batch's indices (hides idx latency under this batch).
        const int evn = ev + 4 * G;
        if (evn + 3 * G < B) {
            e0 = edge_indices[evn];
            e1 = edge_indices[evn + G];
            e2 = edge_indices[evn + 2 * G];
            e3 = edge_indices[evn + 3 * G];
        }

        // J loads (streaming, L2-friendly).
        const float4* J0 = (const float4*)(J + (size_t)ev0 * KDIM);
        const float4* J1 = (const float4*)(J + (size_t)ev1 * KDIM);
        const float4* J2 = (const float4*)(J + (size_t)ev2 * KDIM);
        const float4* J3 = (const float4*)(J + (size_t)ev3 * KDIM);
        const float4 a0 = J0[0], b0 = J0[1];
        const float4 a1 = J1[0], b1 = J1[1];
        const float4 a2 = J2[0], b2 = J2[1];
        const float4 a3 = J3[0], b3 = J3[1];

        float2 u0, u1, u2, u3;

        u0 = __half22float2(__builtin_bit_cast(__half2, up0.x));
        u1 = __half22float2(__builtin_bit_cast(__half2, up0.y));
        u2 = __half22float2(__builtin_bit_cast(__half2, up0.z));
        u3 = __half22float2(__builtin_bit_cast(__half2, up0.w));
        out[(size_t)ev0 * KDIM + r] =
            u0.x * a0.x + u0.y * a0.y + u1.x * a0.z + u1.y * a0.w +
            u2.x * b0.x + u2.y * b0.y + u3.x * b0.z + u3.y * b0.w;

        u0 = __half22float2(__builtin_bit_cast(__half2, up1.x));
        u1 = __half22float2(__builtin_bit_cast(__half2, up1.y));
        u2 = __half22float2(__builtin_bit_cast(__half2, up1.z));
        u3 = __half22float2(__builtin_bit_cast(__half2, up1.w));
        out[(size_t)ev1 * KDIM + r] =
            u0.x * a1.x + u0.y * a1.y + u1.x * a1.z + u1.y * a1.w +
            u2.x * b1.x + u2.y * b1.y + u3.x * b1.z + u3.y * b1.w;

        u0 = __half22float2(__builtin_bit_cast(__half2, up2.x));
        u1 = __half22float2(__builtin_bit_cast(__half2, up2.y));
        u2 = __half22float2(__builtin_bit_cast(__half2, up2.z));
        u3 = __half22float2(__builtin_bit_cast(__half2, up2.w));
        out[(size_t)ev2 * KDIM + r] =
            u0.x * a2.x + u0.y * a2.y + u1.x * a2.z + u1.y * a2.w +
            u2.x * b2.x + u2.y * b2.y + u3.x * b2.z + u3.y * b2.w;

        u0 = __half22float2(__builtin_bit_cast(__half2, up3.x));
        u1 = __half22float2(__builtin_bit_cast(__half2, up3.y));
        u2 = __half22float2(__builtin_bit_cast(__half2, up3.z));
        u3 = __half22float2(__builtin_bit_cast(__half2, up3.w));
        out[(size_t)ev3 * KDIM + r] =
            u0.x * a3.x + u0.y * a3.y + u1.x * a3.z + u1.y * a3.w +
            u2.x * b3.x + u2.y * b3.y + u3.x * b3.z + u3.y * b3.w;

        ev = evn;
    }

    // Remainder.
    for (; ev < B; ev += G) {
        const int e = edge_indices[ev];
        const uint4 up = *(const uint4*)(U + (size_t)e * MAT + r * KDIM);
        const float4* Jr = (const float4*)(J + (size_t)ev * KDIM);
        const float4 a = Jr[0], b = Jr[1];
        float2 u0 = __half22float2(__builtin_bit_cast(__half2, up.x));
        float2 u1 = __half22float2(__builtin_bit_cast(__half2, up.y));
        float2 u2 = __half22float2(__builtin_bit_cast(__half2, up.z));
        float2 u3 = __half22float2(__builtin_bit_cast(__half2, up.w));
        out[(size_t)ev * KDIM + r] =
            u0.x * a.x + u0.y * a.y + u1.x * a.z + u1.y * a.w +
            u2.x * b.x + u2.y * b.y + u3.x * b.z + u3.y * b.w;
    }
}

extern "C" void kernel_launch(void* const* d_in, const int* in_sizes, int n_in,
                              void* d_out, int out_size, void* d_ws, size_t ws_size,
                              hipStream_t stream) {
    const float* omega_params = (const float*)d_in[0];   // (E, 8, 8) f32
    const float* J            = (const float*)d_in[1];   // (B, 8)    f32
    const int*   edge_indices = (const int*)d_in[2];     // (B,)      int
    // d_in[3] = edges (E,2) — unused by the reference computation.

    const int E = in_sizes[0] / MAT;
    const int B = in_sizes[2];
    float* out = (float*)d_out;

    __half* U = (__half*)d_ws;  // E*64 halves = 64 MB; ws_size is ample.

    // Phase 1: per-edge matrix exponential, 8 lanes per edge, fp16 output.
    {
        int block = 256;
        long long total = (long long)E * KDIM;
        int grid = (int)((total + block - 1) / block);
        expm_edges_kernel<<<grid, block, 0, stream>>>(omega_params, U, E);
    }
    // Phase 2: gathered mat-vec, grid-stride 4096 blocks (2x wave capacity),
    // 4-way + idx pipeline, 8 waves/SIMD target.
    {
        int block = 256;
        int grid = 4096;
        transport_kernel<<<grid, block, 0, stream>>>(U, J, edge_indices, out, B);
    }
}